// Round 6
// baseline (182.650 us; speedup 1.0000x reference)
//
#include <hip/hip_runtime.h>
#include <hip/hip_bf16.h>

// Problem constants: B=4, N=4096, C=768, H=W=128, N0=H*W=16384
#define BB 4
#define NN 4096
#define CC 768
#define HH 128
#define WW 128
#define N0 (HH * WW)
#define HW (HH * WW)
#define EPS 1e-6f
#define NSAMP (BB * N0)          // 65536
#define NPIX  (BB * HW)          // 65536
#define NTOK  (BB * NN)          // 16384

// conv tiling: 8x8 pixel tile x 128-channel slice, f32 LDS halo tile
#define TP 8
#define CSUB 128
#define TROW 132                 // floats per (row,col) cell (528B; 132%32=4 pad)
#define NTILE (HH / TP)          // 16
#define CONV_BLOCKS (BB * (CC / CSUB) * NTILE * NTILE)   // 6144

#define XPB 4                    // pixels per k_xmap block (4 indep gather chains)

// ---------------------------------------------------------------------------
__device__ inline float bf2f(ushort u) {
    unsigned v = ((unsigned)u) << 16;
    return __uint_as_float(v);
}
__device__ inline ushort f2bf(float f) {
    __hip_bfloat16 h = __float2bfloat16(f);   // RNE
    return *reinterpret_cast<ushort*>(&h);
}
__device__ inline float4 us4_to_f4(ushort4 u) {
    float4 r;
    r.x = bf2f(u.x); r.y = bf2f(u.y); r.z = bf2f(u.z); r.w = bf2f(u.w);
    return r;
}

// ---------------------------------------------------------------------------
// K0a: pixel index per sample + integer counts per pixel segment and token segment
__global__ void k_idx(const float* __restrict__ loc,
                      const int* __restrict__ idx_agg,
                      int* __restrict__ idx_hw,
                      int* __restrict__ count_pix,
                      int* __restrict__ count_tok) {
    int i = blockIdx.x * blockDim.x + threadIdx.x;
    if (i >= NSAMP) return;
    float lx = loc[2 * i + 0];
    float ly = loc[2 * i + 1];
    float fx = 0.5f * (lx + 1.0f) * (float)WW - 0.5f;
    float fy = 0.5f * (ly + 1.0f) * (float)HH - 0.5f;
    int px = (int)rintf(fx);                 // round-half-even == jnp.round
    int py = (int)rintf(fy);
    px = min(max(px, 0), WW - 1);
    py = min(max(py, 0), HH - 1);
    int pix = py * WW + px;
    idx_hw[i] = pix;
    int b = i >> 14;                         // N0 = 16384
    atomicAdd(&count_pix[(b << 14) + pix], 1);
    atomicAdd(&count_tok[(b << 12) + idx_agg[i]], 1);
}

// ---------------------------------------------------------------------------
// K0b: 8 independent segment scans (4 pix batches, 4 tok batches); each batch
// segment sums to exactly N0 so segment bases are statically b*N0.
__global__ __launch_bounds__(1024) void k_scan(const int* __restrict__ cnt_pix,
                                               int* __restrict__ off_pix,
                                               const int* __restrict__ cnt_tok,
                                               int* __restrict__ off_tok) {
    __shared__ int wpart[16];
    __shared__ int run_sh;
    int bid = blockIdx.x;                    // 0..3 pix, 4..7 tok
    const int* cnt;
    int* off;
    int n, base, vbase;
    if (bid < 4) {
        cnt = cnt_pix; off = off_pix; n = HW;
        base = bid << 14; vbase = bid << 14;
    } else {
        cnt = cnt_tok; off = off_tok; n = NN;
        base = (bid - 4) << 12; vbase = (bid - 4) << 14;
    }
    int t = threadIdx.x;
    int lane = t & 63;
    int wid = t >> 6;                        // 0..15
    if (t == 0) run_sh = 0;
    __syncthreads();
    for (int it = 0; it < n; it += 1024) {
        int idx = it + t;
        int v = (idx < n) ? cnt[base + idx] : 0;
        int s = v;                           // inclusive wave scan
#pragma unroll
        for (int d = 1; d < 64; d <<= 1) {
            int u = __shfl_up(s, d, 64);
            if (lane >= d) s += u;
        }
        if (lane == 63) wpart[wid] = s;
        __syncthreads();
        if (wid == 0) {                      // scan the 16 wave partials
            int p = (lane < 16) ? wpart[lane] : 0;
#pragma unroll
            for (int d = 1; d < 16; d <<= 1) {
                int u = __shfl_up(p, d, 64);
                if (lane >= d) p += u;
            }
            if (lane < 16) wpart[lane] = p;
        }
        __syncthreads();
        int wbase = (wid == 0) ? 0 : wpart[wid - 1];
        int run = run_sh;
        if (idx < n) off[base + idx] = vbase + run + wbase + s - v;  // exclusive
        __syncthreads();                     // all read run_sh before update
        if (t == 0) run_sh = run + wpart[15];
        __syncthreads();
    }
}

// ---------------------------------------------------------------------------
// K0c: fill CSR sample lists (pixel-ordered and token-ordered)
__global__ void k_fill(const int* __restrict__ idx_hw,
                       const int* __restrict__ idx_agg,
                       const int* __restrict__ off_pix, int* __restrict__ fill_pix,
                       int* __restrict__ list_pix,
                       const int* __restrict__ off_tok, int* __restrict__ fill_tok,
                       int* __restrict__ list_tok) {
    int i = blockIdx.x * blockDim.x + threadIdx.x;
    if (i >= NSAMP) return;
    int b = i >> 14;
    int sp = (b << 14) + idx_hw[i];
    int p = atomicAdd(&fill_pix[sp], 1);
    list_pix[off_pix[sp] + p] = i;
    int st = (b << 12) + idx_agg[i];
    int q = atomicAdd(&fill_tok[st], 1);
    list_tok[off_tok[st] + q] = i;
}

// ---------------------------------------------------------------------------
// K1: build normalized pixel map via gather, bf16 output.
//     4 pixels per block -> 4 independent dependent-load chains (4x MLP);
//     all metadata loads are block-uniform (scalarized by the compiler).
__global__ __launch_bounds__(192) void k_xmap(const float* __restrict__ x,
                                              const int* __restrict__ idx_agg,
                                              const int* __restrict__ count_pix,
                                              const int* __restrict__ off_pix,
                                              const int* __restrict__ list_pix,
                                              ushort* __restrict__ xm) {
    int bi0 = blockIdx.x * XPB;              // 4 consecutive pixels, same batch
    int b = bi0 >> 14;
    int c4 = threadIdx.x;                    // 0..191
    const float* xb = x + (size_t)(b * NN) * CC;

    int kk[XPB], st[XPB];
#pragma unroll
    for (int p = 0; p < XPB; ++p) {
        kk[p] = count_pix[bi0 + p];
        st[p] = off_pix[bi0 + p];
    }
    float4 acc[XPB];
#pragma unroll
    for (int p = 0; p < XPB; ++p) acc[p] = make_float4(0.f, 0.f, 0.f, 0.f);

    int kmax = max(max(kk[0], kk[1]), max(kk[2], kk[3]));
    for (int j = 0; j < kmax; ++j) {
#pragma unroll
        for (int p = 0; p < XPB; ++p) {
            if (j < kk[p]) {
                int i = list_pix[st[p] + j];
                int tok = idx_agg[i];
                float4 v = ((const float4*)(xb + (size_t)tok * CC))[c4];
                acc[p].x += v.x; acc[p].y += v.y;
                acc[p].z += v.z; acc[p].w += v.w;
            }
        }
    }
#pragma unroll
    for (int p = 0; p < XPB; ++p) {
        float inv = 1.0f / ((float)kk[p] + EPS);
        ushort4 o;
        o.x = f2bf(acc[p].x * inv); o.y = f2bf(acc[p].y * inv);
        o.z = f2bf(acc[p].z * inv); o.w = f2bf(acc[p].w * inv);
        ((ushort4*)(xm + (size_t)(bi0 + p) * CC))[c4] = o;
    }
}

// ---------------------------------------------------------------------------
// K2: depthwise 3x3 conv + bias, LDS-tiled (8x8 pixels x 128 ch per block).
//     f32 LDS tile (bf16->f32 converted ONCE at staging; inner loop is pure
//     ds_read_b128 + FMA), register sliding window down the tile.
__global__ __launch_bounds__(256, 3) void k_conv(const ushort* __restrict__ xm,
                                                 const float* __restrict__ w_dw,
                                                 const float* __restrict__ b_dw,
                                                 ushort* __restrict__ ym) {
    __shared__ float tile[(TP + 2) * (TP + 2) * TROW];     // 10*10*132*4 = 52.8 KB

    int f = blockIdx.x;
    f = (f & 7) * (CONV_BLOCKS / 8) + (f >> 3);            // bijective XCD swizzle
    int tx = f & 15;
    int ty = (f >> 4) & 15;
    int cblk = (f >> 8) % 6;
    int b = f / 1536;
    int tid = threadIdx.x;

    int c0g = cblk * CSUB;                                 // global channel base
    const ushort* src = xm + (size_t)(b << 14) * CC + c0g;

    // ---- stage 10x10 halo tile: bf16 load, cvt, f32 LDS store ----
    for (int idx = tid; idx < (TP + 2) * (TP + 2) * (CSUB / 4); idx += 256) {
        int lc = idx & 31;                                 // float4 within cell
        int cell = idx >> 5;                               // 0..99
        int r = cell / (TP + 2);
        int c = cell % (TP + 2);
        int gy = ty * TP + r - 1;
        int gx = tx * TP + c - 1;
        float4 v = {0.f, 0.f, 0.f, 0.f};
        if (gy >= 0 && gy < HH && gx >= 0 && gx < WW) {
            v = us4_to_f4(((const ushort4*)(src + (size_t)(gy * WW + gx) * CC))[lc]);
        }
        ((float4*)(tile + (size_t)cell * TROW))[lc] = v;
    }
    __syncthreads();

    // ---- per-thread: 4 channels (c4), one pixel column (px), walk 8 rows ----
    int c4 = tid & 31;
    int px = tid >> 5;                                     // 0..7

    float wreg[36];                                        // 4 ch x 9 taps
    {
        const float4* wp = (const float4*)(w_dw + (size_t)(c0g + c4 * 4) * 9);
#pragma unroll
        for (int j = 0; j < 9; ++j) ((float4*)wreg)[j] = wp[j];
    }
    float4 bias = ((const float4*)(b_dw + c0g))[c4];

    float4 a[3][3];                                        // rows oy..oy+2, cols px..px+2
#pragma unroll
    for (int i = 0; i < 2; ++i)
#pragma unroll
        for (int j = 0; j < 3; ++j)
            a[i][j] = ((const float4*)(tile + (size_t)(i * (TP + 2) + px + j) * TROW))[c4];

    ushort* dst_base = ym + (size_t)((b << 14) + (ty * TP) * WW + tx * TP + px) * CC
                       + c0g;

#pragma unroll
    for (int oy = 0; oy < TP; ++oy) {
#pragma unroll
        for (int j = 0; j < 3; ++j)
            a[2][j] = ((const float4*)(tile + (size_t)((oy + 2) * (TP + 2) + px + j) * TROW))[c4];

        float4 acc = bias;
#pragma unroll
        for (int i = 0; i < 3; ++i) {
#pragma unroll
            for (int j = 0; j < 3; ++j) {
                int t = i * 3 + j;
                acc.x += a[i][j].x * wreg[0 * 9 + t];
                acc.y += a[i][j].y * wreg[1 * 9 + t];
                acc.z += a[i][j].z * wreg[2 * 9 + t];
                acc.w += a[i][j].w * wreg[3 * 9 + t];
            }
        }
        ushort4 o;
        o.x = f2bf(acc.x); o.y = f2bf(acc.y); o.z = f2bf(acc.z); o.w = f2bf(acc.w);
        ((ushort4*)(dst_base + (size_t)oy * WW * CC))[c4] = o;

#pragma unroll
        for (int j = 0; j < 3; ++j) {
            a[0][j] = a[1][j];
            a[1][j] = a[2][j];
        }
    }
}

// ---------------------------------------------------------------------------
// K3: per-token gather of its samples' conv rows, weighted avg, fused skip.
__global__ __launch_bounds__(192) void k_token(const ushort* __restrict__ ym,
                                               const float* __restrict__ x,
                                               const float* __restrict__ agg_w,
                                               const int* __restrict__ idx_hw,
                                               const int* __restrict__ count_tok,
                                               const int* __restrict__ off_tok,
                                               const int* __restrict__ list_tok,
                                               const float* __restrict__ w_skip,
                                               float* __restrict__ out) {
    int bi = blockIdx.x;                     // b*NN + tok
    int b = bi >> 12;                        // NN = 4096
    int c4 = threadIdx.x;
    int k = count_tok[bi];
    int st = off_tok[bi];
    float4 acc = {0.f, 0.f, 0.f, 0.f};
    float tw = 0.f;
    for (int j = 0; j < k; ++j) {
        int i = list_tok[st + j];
        float w = agg_w[i];
        int pix = idx_hw[i];
        float4 v = us4_to_f4(((const ushort4*)(ym + (size_t)((b << 14) + pix) * CC))[c4]);
        acc.x += w * v.x; acc.y += w * v.y; acc.z += w * v.z; acc.w += w * v.w;
        tw += w;
    }
    float inv = 1.0f / (tw + EPS);
    float4 xv = ((const float4*)(x + (size_t)bi * CC))[c4];
    float4 ws = ((const float4*)w_skip)[c4];
    float4 o;
    o.x = acc.x * inv + xv.x * ws.x;
    o.y = acc.y * inv + xv.y * ws.y;
    o.z = acc.z * inv + xv.z * ws.z;
    o.w = acc.w * inv + xv.w * ws.w;
    ((float4*)(out + (size_t)bi * CC))[c4] = o;
}

// ---------------------------------------------------------------------------
extern "C" void kernel_launch(void* const* d_in, const int* in_sizes, int n_in,
                              void* d_out, int out_size, void* d_ws, size_t ws_size,
                              hipStream_t stream) {
    const float* x       = (const float*)d_in[0];   // [B,N,C]
    const float* loc     = (const float*)d_in[1];   // [B,N0,2]
    const int*   idx_agg = (const int*)d_in[2];     // [B,N0]
    const float* agg_w   = (const float*)d_in[3];   // [B,N0]
    const float* w_dw    = (const float*)d_in[6];   // [C,1,3,3]
    const float* b_dw    = (const float*)d_in[7];   // [C]
    const float* w_skip  = (const float*)d_in[8];   // [C]
    float* out = (float*)d_out;
    char* ws = (char*)d_ws;

    size_t off = 0;
    // zeroed region (one small memset): counts + fill cursors
    int* count_pix = (int*)(ws + off); off += (size_t)NPIX * 4;
    int* fill_pix  = (int*)(ws + off); off += (size_t)NPIX * 4;
    int* count_tok = (int*)(ws + off); off += (size_t)NTOK * 4;
    int* fill_tok  = (int*)(ws + off); off += (size_t)NTOK * 4;
    size_t zero_bytes = off;
    // fully-written regions
    int* idx_hw   = (int*)(ws + off); off += (size_t)NSAMP * 4;
    int* off_pix  = (int*)(ws + off); off += (size_t)NPIX * 4;
    int* list_pix = (int*)(ws + off); off += (size_t)NSAMP * 4;
    int* off_tok  = (int*)(ws + off); off += (size_t)NTOK * 4;
    int* list_tok = (int*)(ws + off); off += (size_t)NSAMP * 4;
    ushort* xm = (ushort*)(ws + off); off += (size_t)NPIX * CC * 2;   // 100.7 MB bf16
    ushort* ym = (ushort*)(ws + off); off += (size_t)NPIX * CC * 2;   // 100.7 MB bf16
    // total ~202.7 MB — within the proven-safe workspace budget (R0 used 252 MB)

    hipMemsetAsync(ws, 0, zero_bytes, stream);

    hipLaunchKernelGGL(k_idx, dim3(NSAMP / 256), dim3(256), 0, stream,
                       loc, idx_agg, idx_hw, count_pix, count_tok);
    hipLaunchKernelGGL(k_scan, dim3(8), dim3(1024), 0, stream,
                       count_pix, off_pix, count_tok, off_tok);
    hipLaunchKernelGGL(k_fill, dim3(NSAMP / 256), dim3(256), 0, stream,
                       idx_hw, idx_agg, off_pix, fill_pix, list_pix,
                       off_tok, fill_tok, list_tok);
    hipLaunchKernelGGL(k_xmap, dim3(NPIX / XPB), dim3(192), 0, stream,
                       x, idx_agg, count_pix, off_pix, list_pix, xm);
    hipLaunchKernelGGL(k_conv, dim3(CONV_BLOCKS), dim3(256), 0, stream,
                       xm, w_dw, b_dw, ym);
    hipLaunchKernelGGL(k_token, dim3(NTOK), dim3(192), 0, stream,
                       ym, x, agg_w, idx_hw, count_tok, off_tok, list_tok,
                       w_skip, out);
}

// Round 8
// 172.748 us; speedup vs baseline: 1.0573x; 1.0573x over previous
//
#include <hip/hip_runtime.h>
#include <hip/hip_bf16.h>

// Problem constants: B=4, N=4096, C=768, H=W=128, N0=H*W=16384
#define BB 4
#define NN 4096
#define CC 768
#define HH 128
#define WW 128
#define N0 (HH * WW)
#define HW (HH * WW)
#define EPS 1e-6f
#define NSAMP (BB * N0)          // 65536
#define NPIX  (BB * HW)          // 65536
#define NTOK  (BB * NN)          // 16384

// conv tiling: 8x8 pixel tile x 128-channel slice, bf16 LDS halo tile
// (R6 lesson: f32 tile halves occupancy and regresses — keep bf16, cvt in loop)
#define TP 8
#define CSUB 128
#define TROWU 132                // ushorts per (row,col) cell (264B, 8B-aligned)
#define NTILE (HH / TP)          // 16
#define CONV_BLOCKS (BB * (CC / CSUB) * NTILE * NTILE)   // 6144

#define XPB 4                    // pixels per k_xmap block (4 indep gather chains)
#define TPB 4                    // tokens per k_token block (4 indep gather chains)

// ---------------------------------------------------------------------------
__device__ inline float bf2f(ushort u) {
    unsigned v = ((unsigned)u) << 16;
    return __uint_as_float(v);
}
__device__ inline ushort f2bf(float f) {
    __hip_bfloat16 h = __float2bfloat16(f);   // RNE
    return *reinterpret_cast<ushort*>(&h);
}
__device__ inline float4 us4_to_f4(ushort4 u) {
    float4 r;
    r.x = bf2f(u.x); r.y = bf2f(u.y); r.z = bf2f(u.z); r.w = bf2f(u.w);
    return r;
}

// ---------------------------------------------------------------------------
// K0a: pixel index per sample + integer counts per pixel segment and token segment
__global__ void k_idx(const float* __restrict__ loc,
                      const int* __restrict__ idx_agg,
                      int* __restrict__ idx_hw,
                      int* __restrict__ count_pix,
                      int* __restrict__ count_tok) {
    int i = blockIdx.x * blockDim.x + threadIdx.x;
    if (i >= NSAMP) return;
    float lx = loc[2 * i + 0];
    float ly = loc[2 * i + 1];
    float fx = 0.5f * (lx + 1.0f) * (float)WW - 0.5f;
    float fy = 0.5f * (ly + 1.0f) * (float)HH - 0.5f;
    int px = (int)rintf(fx);                 // round-half-even == jnp.round
    int py = (int)rintf(fy);
    px = min(max(px, 0), WW - 1);
    py = min(max(py, 0), HH - 1);
    int pix = py * WW + px;
    idx_hw[i] = pix;
    int b = i >> 14;                         // N0 = 16384
    atomicAdd(&count_pix[(b << 14) + pix], 1);
    atomicAdd(&count_tok[(b << 12) + idx_agg[i]], 1);
}

// ---------------------------------------------------------------------------
// K0b: 8 independent segment scans (4 pix batches, 4 tok batches); each batch
// segment sums to exactly N0 so segment bases are statically b*N0.
__global__ __launch_bounds__(1024) void k_scan(const int* __restrict__ cnt_pix,
                                               int* __restrict__ off_pix,
                                               const int* __restrict__ cnt_tok,
                                               int* __restrict__ off_tok) {
    __shared__ int wpart[16];
    __shared__ int run_sh;
    int bid = blockIdx.x;                    // 0..3 pix, 4..7 tok
    const int* cnt;
    int* off;
    int n, base, vbase;
    if (bid < 4) {
        cnt = cnt_pix; off = off_pix; n = HW;
        base = bid << 14; vbase = bid << 14;
    } else {
        cnt = cnt_tok; off = off_tok; n = NN;
        base = (bid - 4) << 12; vbase = (bid - 4) << 14;
    }
    int t = threadIdx.x;
    int lane = t & 63;
    int wid = t >> 6;                        // 0..15
    if (t == 0) run_sh = 0;
    __syncthreads();
    for (int it = 0; it < n; it += 1024) {
        int idx = it + t;
        int v = (idx < n) ? cnt[base + idx] : 0;
        int s = v;                           // inclusive wave scan
#pragma unroll
        for (int d = 1; d < 64; d <<= 1) {
            int u = __shfl_up(s, d, 64);
            if (lane >= d) s += u;
        }
        if (lane == 63) wpart[wid] = s;
        __syncthreads();
        if (wid == 0) {                      // scan the 16 wave partials
            int p = (lane < 16) ? wpart[lane] : 0;
#pragma unroll
            for (int d = 1; d < 16; d <<= 1) {
                int u = __shfl_up(p, d, 64);
                if (lane >= d) p += u;
            }
            if (lane < 16) wpart[lane] = p;
        }
        __syncthreads();
        int wbase = (wid == 0) ? 0 : wpart[wid - 1];
        int run = run_sh;
        if (idx < n) off[base + idx] = vbase + run + wbase + s - v;  // exclusive
        __syncthreads();                     // all read run_sh before update
        if (t == 0) run_sh = run + wpart[15];
        __syncthreads();
    }
}

// ---------------------------------------------------------------------------
// K0c: fill CSR sample lists (pixel-ordered and token-ordered)
__global__ void k_fill(const int* __restrict__ idx_hw,
                       const int* __restrict__ idx_agg,
                       const int* __restrict__ off_pix, int* __restrict__ fill_pix,
                       int* __restrict__ list_pix,
                       const int* __restrict__ off_tok, int* __restrict__ fill_tok,
                       int* __restrict__ list_tok) {
    int i = blockIdx.x * blockDim.x + threadIdx.x;
    if (i >= NSAMP) return;
    int b = i >> 14;
    int sp = (b << 14) + idx_hw[i];
    int p = atomicAdd(&fill_pix[sp], 1);
    list_pix[off_pix[sp] + p] = i;
    int st = (b << 12) + idx_agg[i];
    int q = atomicAdd(&fill_tok[st], 1);
    list_tok[off_tok[st] + q] = i;
}

// ---------------------------------------------------------------------------
// K1: build normalized pixel map via gather, bf16 output.
//     4 pixels per block -> 4 independent dependent-load chains (4x MLP).
__global__ __launch_bounds__(192) void k_xmap(const float* __restrict__ x,
                                              const int* __restrict__ idx_agg,
                                              const int* __restrict__ count_pix,
                                              const int* __restrict__ off_pix,
                                              const int* __restrict__ list_pix,
                                              ushort* __restrict__ xm) {
    int bi0 = blockIdx.x * XPB;              // 4 consecutive pixels, same batch
    int b = bi0 >> 14;
    int c4 = threadIdx.x;                    // 0..191
    const float* xb = x + (size_t)(b * NN) * CC;

    int kk[XPB], st[XPB];
#pragma unroll
    for (int p = 0; p < XPB; ++p) {
        kk[p] = count_pix[bi0 + p];
        st[p] = off_pix[bi0 + p];
    }
    float4 acc[XPB];
#pragma unroll
    for (int p = 0; p < XPB; ++p) acc[p] = make_float4(0.f, 0.f, 0.f, 0.f);

    int kmax = max(max(kk[0], kk[1]), max(kk[2], kk[3]));
    for (int j = 0; j < kmax; ++j) {
#pragma unroll
        for (int p = 0; p < XPB; ++p) {
            if (j < kk[p]) {
                int i = list_pix[st[p] + j];
                int tok = idx_agg[i];
                float4 v = ((const float4*)(xb + (size_t)tok * CC))[c4];
                acc[p].x += v.x; acc[p].y += v.y;
                acc[p].z += v.z; acc[p].w += v.w;
            }
        }
    }
#pragma unroll
    for (int p = 0; p < XPB; ++p) {
        float inv = 1.0f / ((float)kk[p] + EPS);
        ushort4 o;
        o.x = f2bf(acc[p].x * inv); o.y = f2bf(acc[p].y * inv);
        o.z = f2bf(acc[p].z * inv); o.w = f2bf(acc[p].w * inv);
        ((ushort4*)(xm + (size_t)(bi0 + p) * CC))[c4] = o;
    }
}

// ---------------------------------------------------------------------------
// K2: depthwise 3x3 conv + bias, LDS-tiled (8x8 pixels x 128 ch per block),
//     bf16 halo tile in LDS, register sliding window down the tile.
//     (R5-proven config: 26.4 KB LDS, cvt in loop — faster than f32 tile.)
__global__ __launch_bounds__(256, 4) void k_conv(const ushort* __restrict__ xm,
                                                 const float* __restrict__ w_dw,
                                                 const float* __restrict__ b_dw,
                                                 ushort* __restrict__ ym) {
    __shared__ ushort tile[(TP + 2) * (TP + 2) * TROWU];   // 10*10*132*2 = 26.4 KB

    int f = blockIdx.x;
    f = (f & 7) * (CONV_BLOCKS / 8) + (f >> 3);            // bijective XCD swizzle
    int tx = f & 15;
    int ty = (f >> 4) & 15;
    int cblk = (f >> 8) % 6;
    int b = f / 1536;
    int tid = threadIdx.x;

    int c0g = cblk * CSUB;                                 // global channel base
    const ushort* src = xm + (size_t)(b << 14) * CC + c0g;

    // ---- stage 10x10 bf16 halo tile (zero-padded at image edges) ----
    for (int idx = tid; idx < (TP + 2) * (TP + 2) * (CSUB / 4); idx += 256) {
        int lc = idx & 31;                                 // ushort4 within cell
        int cell = idx >> 5;                               // 0..99
        int r = cell / (TP + 2);
        int c = cell % (TP + 2);
        int gy = ty * TP + r - 1;
        int gx = tx * TP + c - 1;
        ushort4 v = {0, 0, 0, 0};
        if (gy >= 0 && gy < HH && gx >= 0 && gx < WW) {
            v = ((const ushort4*)(src + (size_t)(gy * WW + gx) * CC))[lc];
        }
        ((ushort4*)(tile + (size_t)cell * TROWU))[lc] = v;
    }
    __syncthreads();

    // ---- per-thread: 4 channels (c4), one pixel column (px), walk 8 rows ----
    int c4 = tid & 31;
    int px = tid >> 5;                                     // 0..7

    float wreg[36];                                        // 4 ch x 9 taps
    {
        const float4* wp = (const float4*)(w_dw + (size_t)(c0g + c4 * 4) * 9);
#pragma unroll
        for (int j = 0; j < 9; ++j) ((float4*)wreg)[j] = wp[j];
    }
    float4 bias = ((const float4*)(b_dw + c0g))[c4];

    float4 a[3][3];                                        // rows oy..oy+2, cols px..px+2
#pragma unroll
    for (int i = 0; i < 2; ++i)
#pragma unroll
        for (int j = 0; j < 3; ++j)
            a[i][j] = us4_to_f4(((const ushort4*)(tile + (size_t)(i * (TP + 2) + px + j) * TROWU))[c4]);

    ushort* dst_base = ym + (size_t)((b << 14) + (ty * TP) * WW + tx * TP + px) * CC
                       + c0g;

#pragma unroll
    for (int oy = 0; oy < TP; ++oy) {
#pragma unroll
        for (int j = 0; j < 3; ++j)
            a[2][j] = us4_to_f4(((const ushort4*)(tile + (size_t)((oy + 2) * (TP + 2) + px + j) * TROWU))[c4]);

        float4 acc = bias;
#pragma unroll
        for (int i = 0; i < 3; ++i) {
#pragma unroll
            for (int j = 0; j < 3; ++j) {
                int t = i * 3 + j;
                acc.x += a[i][j].x * wreg[0 * 9 + t];
                acc.y += a[i][j].y * wreg[1 * 9 + t];
                acc.z += a[i][j].z * wreg[2 * 9 + t];
                acc.w += a[i][j].w * wreg[3 * 9 + t];
            }
        }
        ushort4 o;
        o.x = f2bf(acc.x); o.y = f2bf(acc.y); o.z = f2bf(acc.z); o.w = f2bf(acc.w);
        ((ushort4*)(dst_base + (size_t)oy * WW * CC))[c4] = o;

#pragma unroll
        for (int j = 0; j < 3; ++j) {
            a[0][j] = a[1][j];
            a[1][j] = a[2][j];
        }
    }
}

// ---------------------------------------------------------------------------
// K3: per-token gather of conv rows, weighted avg, fused skip.
//     4 tokens per block -> 4 independent gather chains (4x MLP);
//     out-writes are 12 KB contiguous per block.
__global__ __launch_bounds__(192) void k_token(const ushort* __restrict__ ym,
                                               const float* __restrict__ x,
                                               const float* __restrict__ agg_w,
                                               const int* __restrict__ idx_hw,
                                               const int* __restrict__ count_tok,
                                               const int* __restrict__ off_tok,
                                               const int* __restrict__ list_tok,
                                               const float* __restrict__ w_skip,
                                               float* __restrict__ out) {
    int bi0 = blockIdx.x * TPB;              // 4 consecutive tokens, same batch
    int b = bi0 >> 12;                       // NN = 4096
    int c4 = threadIdx.x;
    const ushort* yb = ym + (size_t)(b << 14) * CC;

    int kk[TPB], st[TPB];
#pragma unroll
    for (int p = 0; p < TPB; ++p) {
        kk[p] = count_tok[bi0 + p];
        st[p] = off_tok[bi0 + p];
    }
    float4 acc[TPB];
    float tw[TPB];
#pragma unroll
    for (int p = 0; p < TPB; ++p) {
        acc[p] = make_float4(0.f, 0.f, 0.f, 0.f);
        tw[p] = 0.f;
    }

    int kmax = max(max(kk[0], kk[1]), max(kk[2], kk[3]));
    for (int j = 0; j < kmax; ++j) {
#pragma unroll
        for (int p = 0; p < TPB; ++p) {
            if (j < kk[p]) {
                int i = list_tok[st[p] + j];
                float w = agg_w[i];
                int pix = idx_hw[i];
                float4 v = us4_to_f4(((const ushort4*)(yb + (size_t)pix * CC))[c4]);
                acc[p].x += w * v.x; acc[p].y += w * v.y;
                acc[p].z += w * v.z; acc[p].w += w * v.w;
                tw[p] += w;
            }
        }
    }

    float4 ws = ((const float4*)w_skip)[c4];
#pragma unroll
    for (int p = 0; p < TPB; ++p) {
        float inv = 1.0f / (tw[p] + EPS);
        float4 xv = ((const float4*)(x + (size_t)(bi0 + p) * CC))[c4];
        float4 o;
        o.x = acc[p].x * inv + xv.x * ws.x;
        o.y = acc[p].y * inv + xv.y * ws.y;
        o.z = acc[p].z * inv + xv.z * ws.z;
        o.w = acc[p].w * inv + xv.w * ws.w;
        ((float4*)(out + (size_t)(bi0 + p) * CC))[c4] = o;
    }
}

// ---------------------------------------------------------------------------
extern "C" void kernel_launch(void* const* d_in, const int* in_sizes, int n_in,
                              void* d_out, int out_size, void* d_ws, size_t ws_size,
                              hipStream_t stream) {
    const float* x       = (const float*)d_in[0];   // [B,N,C]
    const float* loc     = (const float*)d_in[1];   // [B,N0,2]
    const int*   idx_agg = (const int*)d_in[2];     // [B,N0]
    const float* agg_w   = (const float*)d_in[3];   // [B,N0]
    const float* w_dw    = (const float*)d_in[6];   // [C,1,3,3]
    const float* b_dw    = (const float*)d_in[7];   // [C]
    const float* w_skip  = (const float*)d_in[8];   // [C]
    float* out = (float*)d_out;
    char* ws = (char*)d_ws;

    size_t off = 0;
    // zeroed region (one small memset): counts + fill cursors
    int* count_pix = (int*)(ws + off); off += (size_t)NPIX * 4;
    int* fill_pix  = (int*)(ws + off); off += (size_t)NPIX * 4;
    int* count_tok = (int*)(ws + off); off += (size_t)NTOK * 4;
    int* fill_tok  = (int*)(ws + off); off += (size_t)NTOK * 4;
    size_t zero_bytes = off;
    // fully-written regions
    int* idx_hw   = (int*)(ws + off); off += (size_t)NSAMP * 4;
    int* off_pix  = (int*)(ws + off); off += (size_t)NPIX * 4;
    int* list_pix = (int*)(ws + off); off += (size_t)NSAMP * 4;
    int* off_tok  = (int*)(ws + off); off += (size_t)NTOK * 4;
    int* list_tok = (int*)(ws + off); off += (size_t)NSAMP * 4;
    ushort* xm = (ushort*)(ws + off); off += (size_t)NPIX * CC * 2;   // 100.7 MB bf16
    ushort* ym = (ushort*)(ws + off); off += (size_t)NPIX * CC * 2;   // 100.7 MB bf16
    // total ~202.7 MB — within the proven-safe workspace budget (R0 used 252 MB)

    hipMemsetAsync(ws, 0, zero_bytes, stream);

    hipLaunchKernelGGL(k_idx, dim3(NSAMP / 256), dim3(256), 0, stream,
                       loc, idx_agg, idx_hw, count_pix, count_tok);
    hipLaunchKernelGGL(k_scan, dim3(8), dim3(1024), 0, stream,
                       count_pix, off_pix, count_tok, off_tok);
    hipLaunchKernelGGL(k_fill, dim3(NSAMP / 256), dim3(256), 0, stream,
                       idx_hw, idx_agg, off_pix, fill_pix, list_pix,
                       off_tok, fill_tok, list_tok);
    hipLaunchKernelGGL(k_xmap, dim3(NPIX / XPB), dim3(192), 0, stream,
                       x, idx_agg, count_pix, off_pix, list_pix, xm);
    hipLaunchKernelGGL(k_conv, dim3(CONV_BLOCKS), dim3(256), 0, stream,
                       xm, w_dw, b_dw, ym);
    hipLaunchKernelGGL(k_token, dim3(NTOK / TPB), dim3(192), 0, stream,
                       ym, x, agg_w, idx_hw, count_tok, off_tok, list_tok,
                       w_skip, out);
}